// Round 13
// baseline (235.750 us; speedup 1.0000x reference)
//
#include <hip/hip_runtime.h>

#define BB   8
#define NN   4096
#define CIN  64
#define COUT 128
#define KNN  16
#define NTOT (BB * NN)

typedef _Float16 half8 __attribute__((ext_vector_type(8)));
typedef float f32x4 __attribute__((ext_vector_type(4)));

__device__ __forceinline__ void ce_u32(unsigned &x, unsigned &y) {
    unsigned lo = x < y ? x : y;
    unsigned hi = x < y ? y : x;
    x = lo; y = hi;
}

// Batcher odd-even mergesort, n=16: 63 CE. All indices compile-time.
__device__ __forceinline__ void batcher_sort16(unsigned a[16]) {
#pragma unroll
    for (int p = 1; p < 16; p <<= 1) {
#pragma unroll
        for (int k = p; k >= 1; k >>= 1) {
#pragma unroll
            for (int j = k & (p - 1); j + k < 16; j += 2 * k) {
#pragma unroll
                for (int i = 0; i < k; ++i) {
                    if (i + j + k < 16 &&
                        (i + j) / (2 * p) == (i + j + k) / (2 * p))
                        ce_u32(a[i + j], a[i + j + k]);
                }
            }
        }
    }
}

// ---------------------------------------------------------------------------
// Kernel 1: per-point sqnorm + fp16 x (xh) + fp16 -2x (xh2). Block 0 converts
// W to fp16 and zeroes BN stats. (R8-proven)
// ---------------------------------------------------------------------------
__global__ __launch_bounds__(256) void prep_kernel(
    const float* __restrict__ x, const float* __restrict__ W,
    float* __restrict__ sq, _Float16* __restrict__ xh,
    _Float16* __restrict__ xh2, _Float16* __restrict__ Wh,
    float* __restrict__ stats)
{
    int i = blockIdx.x * 256 + threadIdx.x;            // point id
    const float4* xr = (const float4*)(x + (size_t)i * CIN);
    half8* xw  = (half8*)(xh  + (size_t)i * CIN);
    half8* xw2 = (half8*)(xh2 + (size_t)i * CIN);
    float s0 = 0.f, s1 = 0.f;
#pragma unroll
    for (int j = 0; j < 8; ++j) {
        float4 a = xr[2 * j], b = xr[2 * j + 1];
        s0 = fmaf(a.x, a.x, s0); s0 = fmaf(a.y, a.y, s0);
        s0 = fmaf(a.z, a.z, s0); s0 = fmaf(a.w, a.w, s0);
        s1 = fmaf(b.x, b.x, s1); s1 = fmaf(b.y, b.y, s1);
        s1 = fmaf(b.z, b.z, s1); s1 = fmaf(b.w, b.w, s1);
        half8 h, h2;
        h[0] = (_Float16)a.x; h[1] = (_Float16)a.y;
        h[2] = (_Float16)a.z; h[3] = (_Float16)a.w;
        h[4] = (_Float16)b.x; h[5] = (_Float16)b.y;
        h[6] = (_Float16)b.z; h[7] = (_Float16)b.w;
#pragma unroll
        for (int e = 0; e < 8; ++e) h2[e] = (_Float16)(-2.0f) * h[e];
        xw[j] = h; xw2[j] = h2;
    }
    sq[i] = s0 + s1;

    if (blockIdx.x == 0) {
        int t = threadIdx.x;
        stats[t] = 0.0f;                               // sum[128], sumsq[128]
        const float4* wp4 = (const float4*)W;
        half8* wh8 = (half8*)Wh;
#pragma unroll
        for (int j = 0; j < 4; ++j) {
            int idx = t * 4 + j;
            float4 a = wp4[2 * idx], b = wp4[2 * idx + 1];
            half8 h;
            h[0] = (_Float16)a.x; h[1] = (_Float16)a.y;
            h[2] = (_Float16)a.z; h[3] = (_Float16)a.w;
            h[4] = (_Float16)b.x; h[5] = (_Float16)b.y;
            h[6] = (_Float16)b.z; h[7] = (_Float16)b.w;
            wh8[idx] = h;
        }
    }
}

// ---------------------------------------------------------------------------
// Kernel 2: MFMA kNN scan — ONE barrier per chunk.
// Selection remap: wave w's MFMA computes rows [16w,16w+16); lane l now owns
// stream (point = 16w + (l&15), strip = l>>4), i.e. exactly the s_key rows
// this wave wrote -> the epilogue->selection LDS dependency is within-wave
// (lgkmcnt-ordered, no barrier). Stream partition (by col strip) and sub_k
// layout are unchanged -> output bit-identical to R11.
// ---------------------------------------------------------------------------
__global__ __launch_bounds__(256, 4) void knn_scan_mfma_kernel(
    const _Float16* __restrict__ xh, const _Float16* __restrict__ xh2,
    const float* __restrict__ sq, unsigned* __restrict__ sub_k)
{
    __shared__ _Float16 sBT[2][8][64][8];  // 16 KB dbuf
    __shared__ unsigned s_key[64 * 68];    // 17 KB [row][col] stride 68
    __shared__ float    s_sqm[2][64];

    int blk  = blockIdx.x;
    int tile = blk >> 1;
    int half = blk & 1;
    int b    = tile >> 6;
    int n0   = (tile & 63) * 64;
    int t    = threadIdx.x;
    int l    = t & 63;
    int w    = t >> 6;
    int quad = l >> 4;
    int c16  = l & 15;

    // selection stream owned by this lane: point = MFMA A-row, strip = quad
    int psel = 16 * w + c16;
    int qsel = quad;

    const _Float16* xhb  = xh  + (size_t)b * NN * CIN;
    const _Float16* xh2b = xh2 + (size_t)b * NN * CIN;
    const float*    sqb  = sq + (size_t)b * NN;

    float sqn_r[4];
#pragma unroll
    for (int r = 0; r < 4; ++r)
        sqn_r[r] = sqb[n0 + 16 * w + 4 * quad + r];

    int row_a = n0 + 16 * w + c16;
    half8 afrag0 = *(const half8*)(xh2b + (size_t)row_a * CIN + 0 * 32 + quad * 8);
    half8 afrag1 = *(const half8*)(xh2b + (size_t)row_a * CIN + 1 * 32 + quad * 8);

    unsigned best[16];
#pragma unroll
    for (int j = 0; j < 16; ++j) best[j] = 0xFFFFFFFFu;

    {
        int cb0 = half * 2048;
#pragma unroll
        for (int r2 = 0; r2 < 2; ++r2) {
            int f = r2 * 256 + t;
            int cand = f >> 3, g = f & 7;
            *(half8*)&sBT[0][g][cand][0] =
                *(const half8*)(xhb + (size_t)(cb0 + cand) * CIN + g * 8);
        }
        if (t < 64) s_sqm[0][t] = sqb[cb0 + t];
    }

#pragma unroll 1
    for (int c = 0; c < 32; ++c) {
        int cur = c & 1;
        int cbase = half * 2048 + c * 64;
        // single barrier/chunk: guards (a) sBT[cur]/s_sqm[cur] staged by all
        // threads, (b) prior chunk's MFMA reads of sBT[cur^1] done before we
        // overwrite it below. s_key needs no barrier (within-wave only).
        __syncthreads();

        half8 st0, st1; float sqm_n = 0.f;
        int cand0 = t >> 3, g0 = t & 7;
        int cand1 = (256 + t) >> 3, g1 = t & 7;
        bool do_stage = (c < 31);
        if (do_stage) {
            int cb_n = cbase + 64;
            st0 = *(const half8*)(xhb + (size_t)(cb_n + cand0) * CIN + g0 * 8);
            st1 = *(const half8*)(xhb + (size_t)(cb_n + cand1) * CIN + g1 * 8);
            if (t < 64) sqm_n = sqb[cb_n + t];
        }

        f32x4 acc[4];
#pragma unroll
        for (int n = 0; n < 4; ++n) {
            float sm = s_sqm[cur][16 * n + c16];
            f32x4 ci;
            ci[0] = sqn_r[0] + sm; ci[1] = sqn_r[1] + sm;
            ci[2] = sqn_r[2] + sm; ci[3] = sqn_r[3] + sm;
            half8 b0 = *(const half8*)&sBT[cur][0 * 4 + quad][16 * n + c16][0];
            half8 b1 = *(const half8*)&sBT[cur][1 * 4 + quad][16 * n + c16][0];
            ci = __builtin_amdgcn_mfma_f32_16x16x32_f16(afrag0, b0, ci, 0, 0, 0);
            ci = __builtin_amdgcn_mfma_f32_16x16x32_f16(afrag1, b1, ci, 0, 0, 0);
            acc[n] = ci;
        }

        if (do_stage) {
            *(half8*)&sBT[cur ^ 1][g0][cand0][0] = st0;
            *(half8*)&sBT[cur ^ 1][g1][cand1][0] = st1;
            if (t < 64) s_sqm[cur ^ 1][t] = sqm_n;
        }

        // epilogue: wave w writes its own rows [16w,16w+16) of s_key
#pragma unroll
        for (int n = 0; n < 4; ++n) {
            int col = 16 * n + c16;
            unsigned id = (unsigned)(cbase + col);
#pragma unroll
            for (int r = 0; r < 4; ++r) {
                int row = 16 * w + 4 * quad + r;
                float d = fmaxf(acc[n][r], 0.0f);
                s_key[row * 68 + col] = (__float_as_uint(d) & 0xFFFFF000u) | id;
            }
        }
        // NO barrier: selection below reads only this wave's writes

        unsigned a16[16];
#pragma unroll
        for (int j = 0; j < 4; ++j) {
            uint4 v = *(const uint4*)&s_key[psel * 68 + qsel * 16 + 4 * j];
            a16[4 * j + 0] = v.x; a16[4 * j + 1] = v.y;
            a16[4 * j + 2] = v.z; a16[4 * j + 3] = v.w;
        }
        batcher_sort16(a16);
        unsigned m16[16];
#pragma unroll
        for (int i = 0; i < 16; ++i)
            m16[i] = best[i] < a16[15 - i] ? best[i] : a16[15 - i];
#pragma unroll
        for (int d = 8; d > 0; d >>= 1) {
#pragma unroll
            for (int i = 0; i < 16; ++i) {
                if ((i & d) == 0) ce_u32(m16[i], m16[i | d]);
            }
        }
#pragma unroll
        for (int i = 0; i < 16; ++i) best[i] = m16[i];
    }

    size_t base = (((size_t)b * NN + n0 + psel) * 8 + half * 4 + qsel) * 12;
    uint4* dst = (uint4*)(sub_k + base);
    dst[0] = make_uint4(best[0], best[1], best[2],  best[3]);
    dst[1] = make_uint4(best[4], best[5], best[6],  best[7]);
    dst[2] = make_uint4(best[8], best[9], best[10], best[11]);
}

// ---------------------------------------------------------------------------
// Kernel 3: rescue + gather + max-pool + conv MFMA + BN-stats (R10/R11-proven)
// ---------------------------------------------------------------------------
__global__ __launch_bounds__(256, 2) void rescue_pool_gemm_stats_kernel(
    const float* __restrict__ x, const _Float16* __restrict__ xh,
    const float* __restrict__ sq, const unsigned* __restrict__ sub_k,
    const _Float16* __restrict__ Wh, const float* __restrict__ bias,
    _Float16* __restrict__ ph, float* __restrict__ stats)
{
    __shared__ union {
        struct {
            unsigned s_pk[4][64][17];            // 17.0 KB
            unsigned short s_cand[64][26];       //  3.3 KB
            unsigned long long s_ek[4][64][6];   // 12.0 KB
        } a;                                     // rescue phases P1-P4a
        struct {
            float s_red[16][130][2];             // 16.6 KB
        } b;                                     // stats phase (after P4a)
    } u;
    __shared__ int s_out[64][KNN];               //  4.0 KB
    __shared__ _Float16 sPH[64][72];             //  9.2 KB (stride 72)
    __shared__ float s_bias[128];                //  0.5 KB

    int blk = blockIdx.x;
    int b   = blk >> 6;
    int n0  = (blk & 63) * 64;
    int t   = threadIdx.x;
    int p   = t & 63;
    int sub = t >> 6;
    int w   = t >> 6, l = t & 63, quad = l >> 4, c16 = l & 15;
    const float*    xb  = x  + (size_t)b * NN * CIN;
    const _Float16* xhb = xh + (size_t)b * NN * CIN;
    const float*    sqb = sq + (size_t)b * NN;
    size_t gp = (size_t)b * NN + n0 + p;

    if (t < 128) s_bias[t] = bias[t];

    // query row in registers
    float xn[CIN];
    {
        const float4* xr = (const float4*)(xb + (size_t)(n0 + p) * CIN);
#pragma unroll
        for (int j = 0; j < CIN / 4; ++j) {
            float4 v = xr[j];
            xn[4 * j + 0] = v.x; xn[4 * j + 1] = v.y;
            xn[4 * j + 2] = v.z; xn[4 * j + 3] = v.w;
        }
    }
    float sqn = sqb[n0 + p];

    // P1: bitonic merge of two sorted-12 streams -> sorted lowest-16 of 24
    {
        const uint4* kp = (const uint4*)(sub_k + gp * 96 + sub * 24);
        uint4 v0 = kp[0], v1 = kp[1], v2 = kp[2];
        uint4 v3 = kp[3], v4 = kp[4], v5 = kp[5];
        unsigned A[16] = { v0.x, v0.y, v0.z, v0.w, v1.x, v1.y, v1.z, v1.w,
                           v2.x, v2.y, v2.z, v2.w,
                           0xFFFFFFFFu, 0xFFFFFFFFu, 0xFFFFFFFFu, 0xFFFFFFFFu };
        unsigned B[16] = { v3.x, v3.y, v3.z, v3.w, v4.x, v4.y, v4.z, v4.w,
                           v5.x, v5.y, v5.z, v5.w,
                           0xFFFFFFFFu, 0xFFFFFFFFu, 0xFFFFFFFFu, 0xFFFFFFFFu };
        unsigned m[16];
#pragma unroll
        for (int i = 0; i < 16; ++i) m[i] = A[i] < B[15 - i] ? A[i] : B[15 - i];
#pragma unroll
        for (int d = 8; d > 0; d >>= 1) {
#pragma unroll
            for (int i = 0; i < 16; ++i) {
                if ((i & d) == 0) ce_u32(m[i], m[i | d]);
            }
        }
#pragma unroll
        for (int j = 0; j < 16; ++j) u.a.s_pk[sub][p][j] = m[j];
    }
    __syncthreads();

    // P2: 4-way merge -> top-24 ids
    if (t < 64) {
        int p0 = 0, p1 = 0, p2 = 0, p3 = 0;
#pragma unroll 1
        for (int k = 0; k < 24; ++k) {
            unsigned k0 = (p0 < 16) ? u.a.s_pk[0][t][p0] : 0xFFFFFFFFu;
            unsigned k1 = (p1 < 16) ? u.a.s_pk[1][t][p1] : 0xFFFFFFFFu;
            unsigned k2 = (p2 < 16) ? u.a.s_pk[2][t][p2] : 0xFFFFFFFFu;
            unsigned k3 = (p3 < 16) ? u.a.s_pk[3][t][p3] : 0xFFFFFFFFu;
            unsigned bk = k0; int bq = 0;
            if (k1 < bk) { bk = k1; bq = 1; }
            if (k2 < bk) { bk = k2; bq = 2; }
            if (k3 < bk) { bk = k3; bq = 3; }
            u.a.s_cand[t][k] = (unsigned short)(bk & 0xFFFu);
            if (bq == 0) ++p0; else if (bq == 1) ++p1; else if (bq == 2) ++p2; else ++p3;
        }
    }
    __syncthreads();

    // P3: exact fp32 distances for 6 ids/thread, reference-faithful 64-bit keys
    {
        unsigned long long b6[6];
#pragma unroll
        for (int j = 0; j < 6; ++j) b6[j] = ~0ULL;
#pragma unroll 1
        for (int j = 0; j < 6; ++j) {
            int m = u.a.s_cand[p][sub * 6 + j];
            const float4* xm4 = (const float4*)(xb + (size_t)m * CIN);
            float d0 = 0.f, d1 = 0.f, d2 = 0.f, d3 = 0.f;
#pragma unroll
            for (int cc = 0; cc < CIN / 4; ++cc) {
                float4 v = xm4[cc];
                d0 = fmaf(xn[4 * cc + 0], v.x, d0);
                d1 = fmaf(xn[4 * cc + 1], v.y, d1);
                d2 = fmaf(xn[4 * cc + 2], v.z, d2);
                d3 = fmaf(xn[4 * cc + 3], v.w, d3);
            }
            float d = sqn + sqb[m] - 2.0f * ((d0 + d1) + (d2 + d3));
            unsigned bbits = __float_as_uint(d);
            unsigned sgn   = (unsigned)((int)bbits >> 31);
            unsigned uu    = bbits ^ (sgn | 0x80000000u);
            unsigned long long cur = ((unsigned long long)uu << 32) | (unsigned)m;
#pragma unroll
            for (int s = 0; s < 6; ++s) {
                unsigned long long lo = cur < b6[s] ? cur : b6[s];
                unsigned long long hi = cur < b6[s] ? b6[s] : cur;
                b6[s] = lo; cur = hi;
            }
        }
#pragma unroll
        for (int j = 0; j < 6; ++j) u.a.s_ek[sub][p][j] = b6[j];
    }
    __syncthreads();

    // P4a: 4-way merge -> exact top-16 ids
    if (t < 64) {
        int p0 = 0, p1 = 0, p2 = 0, p3 = 0;
#pragma unroll 1
        for (int k = 0; k < KNN; ++k) {
            unsigned long long k0 = (p0 < 6) ? u.a.s_ek[0][t][p0] : ~0ULL;
            unsigned long long k1 = (p1 < 6) ? u.a.s_ek[1][t][p1] : ~0ULL;
            unsigned long long k2 = (p2 < 6) ? u.a.s_ek[2][t][p2] : ~0ULL;
            unsigned long long k3 = (p3 < 6) ? u.a.s_ek[3][t][p3] : ~0ULL;
            unsigned long long bk = k0; int bq = 0;
            if (k1 < bk) { bk = k1; bq = 1; }
            if (k2 < bk) { bk = k2; bq = 2; }
            if (k3 < bk) { bk = k3; bq = 3; }
            s_out[t][k] = (int)(bk & 0xFFFu);
            if (bq == 0) ++p0; else if (bq == 1) ++p1; else if (bq == 2) ++p2; else ++p3;
        }
    }
    __syncthreads();                               // last read of union.a done

    // P4b: gather fp16 rows + max-pool -> LDS sPH + global ph (for pass 2)
    {
        int pp = t >> 2;
        int cg = (t & 3) * 16;
        size_t gp2 = (size_t)b * NN + n0 + pp;
        const half8* r0p = (const half8*)(xhb + (size_t)s_out[pp][0] * CIN + cg);
        half8 m0 = r0p[0], m1 = r0p[1];
#pragma unroll 1
        for (int k = 1; k < KNN; ++k) {
            const half8* src = (const half8*)(xhb + (size_t)s_out[pp][k] * CIN + cg);
            half8 v0 = src[0], v1 = src[1];
#pragma unroll
            for (int e = 0; e < 8; ++e) {
                m0[e] = v0[e] > m0[e] ? v0[e] : m0[e];
                m1[e] = v1[e] > m1[e] ? v1[e] : m1[e];
            }
        }
        *(half8*)&sPH[pp][cg]     = m0;
        *(half8*)&sPH[pp][cg + 8] = m1;
        half8* dst = (half8*)(ph + gp2 * CIN + cg);
        dst[0] = m0; dst[1] = m1;
    }
    __syncthreads();

    // conv1x1 MFMA: A from sPH, B = Wh rows (L2-hot)
    half8 a0 = *(const half8*)&sPH[16 * w + c16][quad * 8];
    half8 a1 = *(const half8*)&sPH[16 * w + c16][32 + quad * 8];

    f32x4 acc[8];
#pragma unroll
    for (int n = 0; n < 8; ++n) acc[n] = (f32x4){0.f, 0.f, 0.f, 0.f};
#pragma unroll
    for (int n = 0; n < 8; ++n) {
        const _Float16* wrow = Wh + (size_t)(16 * n + c16) * CIN;
        half8 b0 = *(const half8*)(wrow + quad * 8);
        half8 b1 = *(const half8*)(wrow + 32 + quad * 8);
        acc[n] = __builtin_amdgcn_mfma_f32_16x16x32_f16(a0, b0, acc[n], 0, 0, 0);
        acc[n] = __builtin_amdgcn_mfma_f32_16x16x32_f16(a1, b1, acc[n], 0, 0, 0);
    }
    __syncthreads();                               // union.a dead -> union.b live

    int idx16 = w * 4 + quad;
#pragma unroll
    for (int n = 0; n < 8; ++n) {
        int col = 16 * n + c16;
        float bc = s_bias[col];
        float s = 0.f, s2 = 0.f;
#pragma unroll
        for (int r = 0; r < 4; ++r) {
            float v = acc[n][r] + bc;
            s += v; s2 = fmaf(v, v, s2);
        }
        u.b.s_red[idx16][col][0] = s;
        u.b.s_red[idx16][col][1] = s2;
    }
    __syncthreads();

    if (t < 128) {
        float S = 0.f, S2 = 0.f;
#pragma unroll
        for (int i = 0; i < 16; ++i) { S += u.b.s_red[i][t][0]; S2 += u.b.s_red[i][t][1]; }
        atomicAdd(&stats[t], S);
        atomicAdd(&stats[COUT + t], S2);
    }
}

// ---------------------------------------------------------------------------
// Kernel 4: recompute identical MFMA y, fuse BN + ReLU -> out. 64-thread
// blocks (one wave = one 16-row tile), grid 2048 -> 8 blocks/CU. (R11)
// ---------------------------------------------------------------------------
__global__ __launch_bounds__(64, 4) void gemm_bn_out_kernel(
    const _Float16* __restrict__ ph, const _Float16* __restrict__ Wh,
    const float* __restrict__ stats, const float* __restrict__ bias,
    const float* __restrict__ gamma, const float* __restrict__ beta,
    float* __restrict__ out)
{
    __shared__ float sS[128];
    __shared__ float sT[128];

    size_t r0 = (size_t)blockIdx.x * 16;
    int l = threadIdx.x;
    int quad = l >> 4, c16 = l & 15;

    {
        const float invN = 1.0f / (float)NTOT;
#pragma unroll
        for (int h = 0; h < 2; ++h) {
            int ch = l + 64 * h;
            float mean = stats[ch] * invN;
            float var  = stats[COUT + ch] * invN - mean * mean;
            float S    = gamma[ch] * rsqrtf(var + 1e-5f);
            sS[ch] = S;
            sT[ch] = beta[ch] + (bias[ch] - mean) * S;
        }
    }

    const _Float16* arow = ph + (r0 + c16) * CIN;
    half8 a0 = *(const half8*)(arow + quad * 8);
    half8 a1 = *(const half8*)(arow + 32 + quad * 8);

    f32x4 acc[8];
#pragma unroll
    for (int n = 0; n < 8; ++n) acc[n] = (f32x4){0.f, 0.f, 0.f, 0.f};
#pragma unroll
    for (int n = 0; n < 8; ++n) {
        const _Float16* wrow = Wh + (size_t)(16 * n + c16) * CIN;
        half8 b0 = *(const half8*)(wrow + quad * 8);
        half8 b1 = *(const half8*)(wrow + 32 + quad * 8);
        acc[n] = __builtin_amdgcn_mfma_f32_16x16x32_f16(a0, b0, acc[n], 0, 0, 0);
        acc[n] = __builtin_amdgcn_mfma_f32_16x16x32_f16(a1, b1, acc[n], 0, 0, 0);
    }
    __syncthreads();

#pragma unroll
    for (int n = 0; n < 8; ++n) {
        int col = 16 * n + c16;
        float Sc = sS[col], Tc = sT[col];
#pragma unroll
        for (int r = 0; r < 4; ++r) {
            int row = quad * 4 + r;
            out[(r0 + row) * COUT + col] = fmaxf(fmaf(acc[n][r], Sc, Tc), 0.0f);
        }
    }
}

// ---------------------------------------------------------------------------
// ws layout (24.25 MiB max; 25 MiB known-safe):
//   [0, 128K)              sq (fp32)
//   [128K, 129K)           stats (sum[128], sumsq[128])
//   [160K, 176K)           Wh (fp16)
//   [256K, 4.25M)          xh  (fp16 x)
//   [4.25M, 8.25M)         xh2 (fp16 -2x)
//   [8.25M, 20.25M)        sub_k (u32, 32768 x 96)
//   [20.25M, 24.25M)       ph (fp16 pooled)
// ---------------------------------------------------------------------------
extern "C" void kernel_launch(void* const* d_in, const int* in_sizes, int n_in,
                              void* d_out, int out_size, void* d_ws, size_t ws_size,
                              hipStream_t stream)
{
    const float* x     = (const float*)d_in[0];
    const float* W     = (const float*)d_in[1];
    const float* bias  = (const float*)d_in[2];
    const float* gamma = (const float*)d_in[3];
    const float* beta  = (const float*)d_in[4];
    float* out = (float*)d_out;

    char* ws = (char*)d_ws;
    float*     sq    = (float*)(ws);
    float*     stats = (float*)(ws + 131072);
    _Float16*  Wh    = (_Float16*)(ws + 163840);
    _Float16*  xh    = (_Float16*)(ws + 262144);
    _Float16*  xh2   = (_Float16*)(ws + 262144 + 4u * 1024 * 1024);
    unsigned*  sub_k = (unsigned*)(ws + 262144 + 8u * 1024 * 1024);
    _Float16*  ph    = (_Float16*)(ws + 262144 + 20u * 1024 * 1024);

    hipLaunchKernelGGL(prep_kernel, dim3(NTOT / 256), dim3(256), 0, stream,
                       x, W, sq, xh, xh2, Wh, stats);
    hipLaunchKernelGGL(knn_scan_mfma_kernel, dim3(NTOT / 64 * 2), dim3(256), 0, stream,
                       xh, xh2, sq, sub_k);
    hipLaunchKernelGGL(rescue_pool_gemm_stats_kernel, dim3(NTOT / 64), dim3(256), 0, stream,
                       x, xh, sq, sub_k, Wh, bias, ph, stats);
    hipLaunchKernelGGL(gemm_bn_out_kernel, dim3(NTOT / 16), dim3(64), 0, stream,
                       ph, Wh, stats, bias, gamma, beta, out);
}

// Round 14
// 223.906 us; speedup vs baseline: 1.0529x; 1.0529x over previous
//
#include <hip/hip_runtime.h>

#define BB   8
#define NN   4096
#define CIN  64
#define COUT 128
#define KNN  16
#define NTOT (BB * NN)

typedef _Float16 half8 __attribute__((ext_vector_type(8)));
typedef float f32x4 __attribute__((ext_vector_type(4)));

__device__ __forceinline__ void ce_u32(unsigned &x, unsigned &y) {
    unsigned lo = x < y ? x : y;
    unsigned hi = x < y ? y : x;
    x = lo; y = hi;
}

// Batcher odd-even mergesort, n=16: 63 CE. All indices compile-time.
__device__ __forceinline__ void batcher_sort16(unsigned a[16]) {
#pragma unroll
    for (int p = 1; p < 16; p <<= 1) {
#pragma unroll
        for (int k = p; k >= 1; k >>= 1) {
#pragma unroll
            for (int j = k & (p - 1); j + k < 16; j += 2 * k) {
#pragma unroll
                for (int i = 0; i < k; ++i) {
                    if (i + j + k < 16 &&
                        (i + j) / (2 * p) == (i + j + k) / (2 * p))
                        ce_u32(a[i + j], a[i + j + k]);
                }
            }
        }
    }
}

// bitonic merge of two ascending sorted-16 lists (A in place, B arg), keep
// lowest 16, result ascending in A.
__device__ __forceinline__ void merge16_lowest(unsigned A[16], const unsigned B[16]) {
    unsigned m[16];
#pragma unroll
    for (int i = 0; i < 16; ++i) m[i] = A[i] < B[15 - i] ? A[i] : B[15 - i];
#pragma unroll
    for (int d = 8; d > 0; d >>= 1) {
#pragma unroll
        for (int i = 0; i < 16; ++i) {
            if ((i & d) == 0) ce_u32(m[i], m[i | d]);
        }
    }
#pragma unroll
    for (int i = 0; i < 16; ++i) A[i] = m[i];
}

// ---------------------------------------------------------------------------
// Kernel 1: per-point sqnorm + fp16 x (xh) + fp16 -2x (xh2). Block 0 converts
// W to fp16 and zeroes BN stats. (R8-proven)
// ---------------------------------------------------------------------------
__global__ __launch_bounds__(256) void prep_kernel(
    const float* __restrict__ x, const float* __restrict__ W,
    float* __restrict__ sq, _Float16* __restrict__ xh,
    _Float16* __restrict__ xh2, _Float16* __restrict__ Wh,
    float* __restrict__ stats)
{
    int i = blockIdx.x * 256 + threadIdx.x;            // point id
    const float4* xr = (const float4*)(x + (size_t)i * CIN);
    half8* xw  = (half8*)(xh  + (size_t)i * CIN);
    half8* xw2 = (half8*)(xh2 + (size_t)i * CIN);
    float s0 = 0.f, s1 = 0.f;
#pragma unroll
    for (int j = 0; j < 8; ++j) {
        float4 a = xr[2 * j], b = xr[2 * j + 1];
        s0 = fmaf(a.x, a.x, s0); s0 = fmaf(a.y, a.y, s0);
        s0 = fmaf(a.z, a.z, s0); s0 = fmaf(a.w, a.w, s0);
        s1 = fmaf(b.x, b.x, s1); s1 = fmaf(b.y, b.y, s1);
        s1 = fmaf(b.z, b.z, s1); s1 = fmaf(b.w, b.w, s1);
        half8 h, h2;
        h[0] = (_Float16)a.x; h[1] = (_Float16)a.y;
        h[2] = (_Float16)a.z; h[3] = (_Float16)a.w;
        h[4] = (_Float16)b.x; h[5] = (_Float16)b.y;
        h[6] = (_Float16)b.z; h[7] = (_Float16)b.w;
#pragma unroll
        for (int e = 0; e < 8; ++e) h2[e] = (_Float16)(-2.0f) * h[e];
        xw[j] = h; xw2[j] = h2;
    }
    sq[i] = s0 + s1;

    if (blockIdx.x == 0) {
        int t = threadIdx.x;
        stats[t] = 0.0f;                               // sum[128], sumsq[128]
        const float4* wp4 = (const float4*)W;
        half8* wh8 = (half8*)Wh;
#pragma unroll
        for (int j = 0; j < 4; ++j) {
            int idx = t * 4 + j;
            float4 a = wp4[2 * idx], b = wp4[2 * idx + 1];
            half8 h;
            h[0] = (_Float16)a.x; h[1] = (_Float16)a.y;
            h[2] = (_Float16)a.z; h[3] = (_Float16)a.w;
            h[4] = (_Float16)b.x; h[5] = (_Float16)b.y;
            h[6] = (_Float16)b.z; h[7] = (_Float16)b.w;
            wh8[idx] = h;
        }
    }
}

// ---------------------------------------------------------------------------
// Kernel 2: MFMA kNN scan — occupancy restructure.
// Block = 128 queries x 512 threads (8 waves); candidates split 3 ways
// (22/21/21 chunks of 64). Grid = 256 tiles x 3 = 768 = exactly 3 blocks/CU
// (LDS 51.3 KB -> 3/CU cap; 24 waves/CU = 6/SIMD vs R13's 4). Wave w owns
// rows [16w,16w+16); lane l owns stream (point=16w+(l&15), strip=l>>4) —
// all s_key traffic wave-private (no selection barrier). At kernel end the
// 4 strips of each point are merged in-wave (2 bitonic rounds via s_key) ->
// per-(point, split) EXACT sorted top-16 -> deterministic coverage of the
// global top-16 (each member is in its split's top-16).
// ---------------------------------------------------------------------------
__global__ __launch_bounds__(512, 6) void knn_scan_mfma_kernel(
    const _Float16* __restrict__ xh, const _Float16* __restrict__ xh2,
    const float* __restrict__ sq, unsigned* __restrict__ sub_k)
{
    __shared__ _Float16 sBT[2][8][64][8];  // 16 KB dbuf [buf][granule][cand][8]
    __shared__ unsigned s_key[128 * 68];   // 34 KB [row][col] stride 68
    __shared__ float    s_sqm[2][64];

    int blk   = blockIdx.x;
    int tile  = blk / 3;                   // 0..255, 128 queries each
    int split = blk - tile * 3;            // candidate third
    int b     = tile >> 5;                 // 32 tiles per batch
    int pn0   = (tile & 31) * 128;         // within-batch query base
    int t     = threadIdx.x;
    int l     = t & 63;
    int w     = t >> 6;                    // wave 0..7 -> rows 16w..16w+16
    int quad  = l >> 4;
    int c16   = l & 15;

    int psel = 16 * w + c16;               // selection point row (0..127)
    int qsel = quad;                       // selection col strip

    int split_start = (split == 0) ? 0 : ((split == 1) ? 1408 : 2752);
    int nch         = (split == 0) ? 22 : 21;

    const _Float16* xhb  = xh  + (size_t)b * NN * CIN;
    const _Float16* xh2b = xh2 + (size_t)b * NN * CIN;
    const float*    sqb  = sq + (size_t)b * NN;

    float sqn_r[4];
#pragma unroll
    for (int r = 0; r < 4; ++r)
        sqn_r[r] = sqb[pn0 + 16 * w + 4 * quad + r];

    int row_a = pn0 + 16 * w + c16;
    half8 afrag0 = *(const half8*)(xh2b + (size_t)row_a * CIN + 0 * 32 + quad * 8);
    half8 afrag1 = *(const half8*)(xh2b + (size_t)row_a * CIN + 1 * 32 + quad * 8);

    unsigned best[16];
#pragma unroll
    for (int j = 0; j < 16; ++j) best[j] = 0xFFFFFFFFu;

    // stage chunk 0: 512 granules, one per thread
    {
        int cand = t >> 3, g = t & 7;
        *(half8*)&sBT[0][g][cand][0] =
            *(const half8*)(xhb + (size_t)(split_start + cand) * CIN + g * 8);
        if (t < 64) s_sqm[0][t] = sqb[split_start + t];
    }

#pragma unroll 1
    for (int c = 0; c < nch; ++c) {
        int cur = c & 1;
        int cbase = split_start + c * 64;
        __syncthreads();                   // staged data ready; prev MFMA done

        // prefetch chunk c+1 into regs (hidden behind MFMA)
        half8 st0; float sqm_n = 0.f;
        int cand0 = t >> 3, g0 = t & 7;
        bool do_stage = (c < nch - 1);
        if (do_stage) {
            int cb_n = cbase + 64;
            st0 = *(const half8*)(xhb + (size_t)(cb_n + cand0) * CIN + g0 * 8);
            if (t < 64) sqm_n = sqb[cb_n + t];
        }

        // MFMA with C = sqn+sqm: acc comes out as the distance directly
        f32x4 acc[4];
#pragma unroll
        for (int n = 0; n < 4; ++n) {
            float sm = s_sqm[cur][16 * n + c16];
            f32x4 ci;
            ci[0] = sqn_r[0] + sm; ci[1] = sqn_r[1] + sm;
            ci[2] = sqn_r[2] + sm; ci[3] = sqn_r[3] + sm;
            half8 b0 = *(const half8*)&sBT[cur][0 * 4 + quad][16 * n + c16][0];
            half8 b1 = *(const half8*)&sBT[cur][1 * 4 + quad][16 * n + c16][0];
            ci = __builtin_amdgcn_mfma_f32_16x16x32_f16(afrag0, b0, ci, 0, 0, 0);
            ci = __builtin_amdgcn_mfma_f32_16x16x32_f16(afrag1, b1, ci, 0, 0, 0);
            acc[n] = ci;
        }

        if (do_stage) {
            *(half8*)&sBT[cur ^ 1][g0][cand0][0] = st0;
            if (t < 64) s_sqm[cur ^ 1][t] = sqm_n;
        }

        // epilogue: wave w writes its own rows of s_key (wave-private)
#pragma unroll
        for (int n = 0; n < 4; ++n) {
            int col = 16 * n + c16;
            unsigned id = (unsigned)(cbase + col);
#pragma unroll
            for (int r = 0; r < 4; ++r) {
                int row = 16 * w + 4 * quad + r;
                float d = fmaxf(acc[n][r], 0.0f);
                s_key[row * 68 + col] = (__float_as_uint(d) & 0xFFFFF000u) | id;
            }
        }
        // NO barrier: selection reads only this wave's writes (DS in-order)

        unsigned a16[16];
#pragma unroll
        for (int j = 0; j < 4; ++j) {
            uint4 v = *(const uint4*)&s_key[psel * 68 + qsel * 16 + 4 * j];
            a16[4 * j + 0] = v.x; a16[4 * j + 1] = v.y;
            a16[4 * j + 2] = v.z; a16[4 * j + 3] = v.w;
        }
        batcher_sort16(a16);
        merge16_lowest(best, a16);
    }

    // in-wave strip merge: 4 sorted-16 lists per point -> exact top-16 of
    // this split. Rounds via wave-private s_key slots (DS in-order, no bar).
#pragma unroll
    for (int j = 0; j < 4; ++j)
        *(uint4*)&s_key[psel * 68 + qsel * 16 + 4 * j] =
            make_uint4(best[4 * j], best[4 * j + 1], best[4 * j + 2], best[4 * j + 3]);
#pragma unroll
    for (int rnd = 0; rnd < 2; ++rnd) {
        int d = 1 << rnd;                  // partner strip 1 then 2
        unsigned Bv[16];
#pragma unroll
        for (int j = 0; j < 4; ++j) {
            uint4 v = *(const uint4*)&s_key[psel * 68 + (qsel ^ d) * 16 + 4 * j];
            Bv[4 * j + 0] = v.x; Bv[4 * j + 1] = v.y;
            Bv[4 * j + 2] = v.z; Bv[4 * j + 3] = v.w;
        }
        merge16_lowest(best, Bv);
        if (rnd == 0) {
#pragma unroll
            for (int j = 0; j < 4; ++j)
                *(uint4*)&s_key[psel * 68 + qsel * 16 + 4 * j] =
                    make_uint4(best[4 * j], best[4 * j + 1],
                               best[4 * j + 2], best[4 * j + 3]);
        }
    }

    if (quad == 0) {                       // one lane per point writes
        size_t gpoint = (size_t)tile * 128 + psel;
        uint4* dst = (uint4*)(sub_k + (gpoint * 3 + split) * 16);
        dst[0] = make_uint4(best[0],  best[1],  best[2],  best[3]);
        dst[1] = make_uint4(best[4],  best[5],  best[6],  best[7]);
        dst[2] = make_uint4(best[8],  best[9],  best[10], best[11]);
        dst[3] = make_uint4(best[12], best[13], best[14], best[15]);
    }
}

// ---------------------------------------------------------------------------
// Kernel 3: rescue + gather + max-pool + conv MFMA + BN-stats.
// P1 is now pure loads: 3 pre-sorted top-16 lists per point (thread 3 = inf).
// ---------------------------------------------------------------------------
__global__ __launch_bounds__(256, 2) void rescue_pool_gemm_stats_kernel(
    const float* __restrict__ x, const _Float16* __restrict__ xh,
    const float* __restrict__ sq, const unsigned* __restrict__ sub_k,
    const _Float16* __restrict__ Wh, const float* __restrict__ bias,
    _Float16* __restrict__ ph, float* __restrict__ stats)
{
    __shared__ union {
        struct {
            unsigned s_pk[4][64][17];            // 17.0 KB
            unsigned short s_cand[64][26];       //  3.3 KB
            unsigned long long s_ek[4][64][6];   // 12.0 KB
        } a;                                     // rescue phases P1-P4a
        struct {
            float s_red[16][130][2];             // 16.6 KB
        } b;                                     // stats phase (after P4a)
    } u;
    __shared__ int s_out[64][KNN];               //  4.0 KB
    __shared__ _Float16 sPH[64][72];             //  9.2 KB (stride 72)
    __shared__ float s_bias[128];                //  0.5 KB

    int blk = blockIdx.x;
    int b   = blk >> 6;
    int n0  = (blk & 63) * 64;
    int t   = threadIdx.x;
    int p   = t & 63;
    int sub = t >> 6;
    int w   = t >> 6, l = t & 63, quad = l >> 4, c16 = l & 15;
    const float*    xb  = x  + (size_t)b * NN * CIN;
    const _Float16* xhb = xh + (size_t)b * NN * CIN;
    const float*    sqb = sq + (size_t)b * NN;
    size_t gp = (size_t)b * NN + n0 + p;

    if (t < 128) s_bias[t] = bias[t];

    // query row in registers
    float xn[CIN];
    {
        const float4* xr = (const float4*)(xb + (size_t)(n0 + p) * CIN);
#pragma unroll
        for (int j = 0; j < CIN / 4; ++j) {
            float4 v = xr[j];
            xn[4 * j + 0] = v.x; xn[4 * j + 1] = v.y;
            xn[4 * j + 2] = v.z; xn[4 * j + 3] = v.w;
        }
    }
    float sqn = sqb[n0 + p];

    // P1: stage the 3 pre-sorted split lists (thread sub==3 -> sentinels)
    if (sub < 3) {
        const uint4* kp = (const uint4*)(sub_k + (gp * 3 + sub) * 16);
        uint4 v0 = kp[0], v1 = kp[1], v2 = kp[2], v3 = kp[3];
        u.a.s_pk[sub][p][0]  = v0.x; u.a.s_pk[sub][p][1]  = v0.y;
        u.a.s_pk[sub][p][2]  = v0.z; u.a.s_pk[sub][p][3]  = v0.w;
        u.a.s_pk[sub][p][4]  = v1.x; u.a.s_pk[sub][p][5]  = v1.y;
        u.a.s_pk[sub][p][6]  = v1.z; u.a.s_pk[sub][p][7]  = v1.w;
        u.a.s_pk[sub][p][8]  = v2.x; u.a.s_pk[sub][p][9]  = v2.y;
        u.a.s_pk[sub][p][10] = v2.z; u.a.s_pk[sub][p][11] = v2.w;
        u.a.s_pk[sub][p][12] = v3.x; u.a.s_pk[sub][p][13] = v3.y;
        u.a.s_pk[sub][p][14] = v3.z; u.a.s_pk[sub][p][15] = v3.w;
    } else {
#pragma unroll
        for (int j = 0; j < 16; ++j) u.a.s_pk[3][p][j] = 0xFFFFFFFFu;
    }
    __syncthreads();

    // P2: 4-way merge -> top-24 ids (stream 3 is all-inf)
    if (t < 64) {
        int p0 = 0, p1 = 0, p2 = 0, p3 = 0;
#pragma unroll 1
        for (int k = 0; k < 24; ++k) {
            unsigned k0 = (p0 < 16) ? u.a.s_pk[0][t][p0] : 0xFFFFFFFFu;
            unsigned k1 = (p1 < 16) ? u.a.s_pk[1][t][p1] : 0xFFFFFFFFu;
            unsigned k2 = (p2 < 16) ? u.a.s_pk[2][t][p2] : 0xFFFFFFFFu;
            unsigned k3 = (p3 < 16) ? u.a.s_pk[3][t][p3] : 0xFFFFFFFFu;
            unsigned bk = k0; int bq = 0;
            if (k1 < bk) { bk = k1; bq = 1; }
            if (k2 < bk) { bk = k2; bq = 2; }
            if (k3 < bk) { bk = k3; bq = 3; }
            u.a.s_cand[t][k] = (unsigned short)(bk & 0xFFFu);
            if (bq == 0) ++p0; else if (bq == 1) ++p1; else if (bq == 2) ++p2; else ++p3;
        }
    }
    __syncthreads();

    // P3: exact fp32 distances for 6 ids/thread, reference-faithful 64-bit keys
    {
        unsigned long long b6[6];
#pragma unroll
        for (int j = 0; j < 6; ++j) b6[j] = ~0ULL;
#pragma unroll 1
        for (int j = 0; j < 6; ++j) {
            int m = u.a.s_cand[p][sub * 6 + j];
            const float4* xm4 = (const float4*)(xb + (size_t)m * CIN);
            float d0 = 0.f, d1 = 0.f, d2 = 0.f, d3 = 0.f;
#pragma unroll
            for (int cc = 0; cc < CIN / 4; ++cc) {
                float4 v = xm4[cc];
                d0 = fmaf(xn[4 * cc + 0], v.x, d0);
                d1 = fmaf(xn[4 * cc + 1], v.y, d1);
                d2 = fmaf(xn[4 * cc + 2], v.z, d2);
                d3 = fmaf(xn[4 * cc + 3], v.w, d3);
            }
            float d = sqn + sqb[m] - 2.0f * ((d0 + d1) + (d2 + d3));
            unsigned bbits = __float_as_uint(d);
            unsigned sgn   = (unsigned)((int)bbits >> 31);
            unsigned uu    = bbits ^ (sgn | 0x80000000u);
            unsigned long long cur = ((unsigned long long)uu << 32) | (unsigned)m;
#pragma unroll
            for (int s = 0; s < 6; ++s) {
                unsigned long long lo = cur < b6[s] ? cur : b6[s];
                unsigned long long hi = cur < b6[s] ? b6[s] : cur;
                b6[s] = lo; cur = hi;
            }
        }
#pragma unroll
        for (int j = 0; j < 6; ++j) u.a.s_ek[sub][p][j] = b6[j];
    }
    __syncthreads();

    // P4a: 4-way merge -> exact top-16 ids
    if (t < 64) {
        int p0 = 0, p1 = 0, p2 = 0, p3 = 0;
#pragma unroll 1
        for (int k = 0; k < KNN; ++k) {
            unsigned long long k0 = (p0 < 6) ? u.a.s_ek[0][t][p0] : ~0ULL;
            unsigned long long k1 = (p1 < 6) ? u.a.s_ek[1][t][p1] : ~0ULL;
            unsigned long long k2 = (p2 < 6) ? u.a.s_ek[2][t][p2] : ~0ULL;
            unsigned long long k3 = (p3 < 6) ? u.a.s_ek[3][t][p3] : ~0ULL;
            unsigned long long bk = k0; int bq = 0;
            if (k1 < bk) { bk = k1; bq = 1; }
            if (k2 < bk) { bk = k2; bq = 2; }
            if (k3 < bk) { bk = k3; bq = 3; }
            s_out[t][k] = (int)(bk & 0xFFFu);
            if (bq == 0) ++p0; else if (bq == 1) ++p1; else if (bq == 2) ++p2; else ++p3;
        }
    }
    __syncthreads();                               // last read of union.a done

    // P4b: gather fp16 rows + max-pool -> LDS sPH + global ph (for pass 2)
    {
        int pp = t >> 2;
        int cg = (t & 3) * 16;
        size_t gp2 = (size_t)b * NN + n0 + pp;
        const half8* r0p = (const half8*)(xhb + (size_t)s_out[pp][0] * CIN + cg);
        half8 m0 = r0p[0], m1 = r0p[1];
#pragma unroll 1
        for (int k = 1; k < KNN; ++k) {
            const half8* src = (const half8*)(xhb + (size_t)s_out[pp][k] * CIN + cg);
            half8 v0 = src[0], v1 = src[1];
#pragma unroll
            for (int e = 0; e < 8; ++e) {
                m0[e] = v0[e] > m0[e] ? v0[e] : m0[e];
                m1[e] = v1[e] > m1[e] ? v1[e] : m1[e];
            }
        }
        *(half8*)&sPH[pp][cg]     = m0;
        *(half8*)&sPH[pp][cg + 8] = m1;
        half8* dst = (half8*)(ph + gp2 * CIN + cg);
        dst[0] = m0; dst[1] = m1;
    }
    __syncthreads();

    // conv1x1 MFMA: A from sPH, B = Wh rows (L2-hot)
    half8 a0 = *(const half8*)&sPH[16 * w + c16][quad * 8];
    half8 a1 = *(const half8*)&sPH[16 * w + c16][32 + quad * 8];

    f32x4 acc[8];
#pragma unroll
    for (int n = 0; n < 8; ++n) acc[n] = (f32x4){0.f, 0.f, 0.f, 0.f};
#pragma unroll
    for (int n = 0; n < 8; ++n) {
        const _Float16* wrow = Wh + (size_t)(16 * n + c16) * CIN;
        half8 b0 = *(const half8*)(wrow + quad * 8);
        half8 b1 = *(const half8*)(wrow + 32 + quad * 8);
        acc[n] = __builtin_amdgcn_mfma_f32_16x16x32_f16(a0, b0, acc[n], 0, 0, 0);
        acc[n] = __builtin_amdgcn_mfma_f32_16x16x32_f16(a1, b1, acc[n], 0, 0, 0);
    }
    __syncthreads();                               // union.a dead -> union.b live

    int idx16 = w * 4 + quad;
#pragma unroll
    for (int n = 0; n < 8; ++n) {
        int col = 16 * n + c16;
        float bc = s_bias[col];
        float s = 0.f, s2 = 0.f;
#pragma unroll
        for (int r = 0; r < 4; ++r) {
            float v = acc[n][r] + bc;
            s += v; s2 = fmaf(v, v, s2);
        }
        u.b.s_red[idx16][col][0] = s;
        u.b.s_red[idx16][col][1] = s2;
    }
    __syncthreads();

    if (t < 128) {
        float S = 0.f, S2 = 0.f;
#pragma unroll
        for (int i = 0; i < 16; ++i) { S += u.b.s_red[i][t][0]; S2 += u.b.s_red[i][t][1]; }
        atomicAdd(&stats[t], S);
        atomicAdd(&stats[COUT + t], S2);
    }
}

// ---------------------------------------------------------------------------
// Kernel 4: recompute identical MFMA y, fuse BN + ReLU -> out. 64-thread
// blocks (one wave = one 16-row tile), grid 2048 -> 8 blocks/CU. (R11)
// ---------------------------------------------------------------------------
__global__ __launch_bounds__(64, 4) void gemm_bn_out_kernel(
    const _Float16* __restrict__ ph, const _Float16* __restrict__ Wh,
    const float* __restrict__ stats, const float* __restrict__ bias,
    const float* __restrict__ gamma, const float* __restrict__ beta,
    float* __restrict__ out)
{
    __shared__ float sS[128];
    __shared__ float sT[128];

    size_t r0 = (size_t)blockIdx.x * 16;
    int l = threadIdx.x;
    int quad = l >> 4, c16 = l & 15;

    {
        const float invN = 1.0f / (float)NTOT;
#pragma unroll
        for (int h = 0; h < 2; ++h) {
            int ch = l + 64 * h;
            float mean = stats[ch] * invN;
            float var  = stats[COUT + ch] * invN - mean * mean;
            float S    = gamma[ch] * rsqrtf(var + 1e-5f);
            sS[ch] = S;
            sT[ch] = beta[ch] + (bias[ch] - mean) * S;
        }
    }

    const _Float16* arow = ph + (r0 + c16) * CIN;
    half8 a0 = *(const half8*)(arow + quad * 8);
    half8 a1 = *(const half8*)(arow + 32 + quad * 8);

    f32x4 acc[8];
#pragma unroll
    for (int n = 0; n < 8; ++n) acc[n] = (f32x4){0.f, 0.f, 0.f, 0.f};
#pragma unroll
    for (int n = 0; n < 8; ++n) {
        const _Float16* wrow = Wh + (size_t)(16 * n + c16) * CIN;
        half8 b0 = *(const half8*)(wrow + quad * 8);
        half8 b1 = *(const half8*)(wrow + 32 + quad * 8);
        acc[n] = __builtin_amdgcn_mfma_f32_16x16x32_f16(a0, b0, acc[n], 0, 0, 0);
        acc[n] = __builtin_amdgcn_mfma_f32_16x16x32_f16(a1, b1, acc[n], 0, 0, 0);
    }
    __syncthreads();

#pragma unroll
    for (int n = 0; n < 8; ++n) {
        int col = 16 * n + c16;
        float Sc = sS[col], Tc = sT[col];
#pragma unroll
        for (int r = 0; r < 4; ++r) {
            int row = quad * 4 + r;
            out[(r0 + row) * COUT + col] = fmaxf(fmaf(acc[n][r], Sc, Tc), 0.0f);
        }
    }
}

// ---------------------------------------------------------------------------
// ws layout (24.25 MiB max; 25 MiB known-safe):
//   [0, 128K)              sq (fp32)
//   [128K, 129K)           stats (sum[128], sumsq[128])
//   [160K, 176K)           Wh (fp16)
//   [256K, 4.25M)          xh  (fp16 x)
//   [4.25M, 8.25M)         xh2 (fp16 -2x)
//   [8.25M, 14.25M)        sub_k (u32, 32768 x 48 = 6 MB)
//   [20.25M, 24.25M)       ph (fp16 pooled)
// ---------------------------------------------------------------------------
extern "C" void kernel_launch(void* const* d_in, const int* in_sizes, int n_in,
                              void* d_out, int out_size, void* d_ws, size_t ws_size,
                              hipStream_t stream)
{
    const float* x     = (const float*)d_in[0];
    const float* W     = (const float*)d_in[1];
    const float* bias  = (const float*)d_in[2];
    const float* gamma = (const float*)d_in[3];
    const float* beta  = (const float*)d_in[4];
    float* out = (float*)d_out;

    char* ws = (char*)d_ws;
    float*     sq    = (float*)(ws);
    float*     stats = (float*)(ws + 131072);
    _Float16*  Wh    = (_Float16*)(ws + 163840);
    _Float16*  xh    = (_Float16*)(ws + 262144);
    _Float16*  xh2   = (_Float16*)(ws + 262144 + 4u * 1024 * 1024);
    unsigned*  sub_k = (unsigned*)(ws + 262144 + 8u * 1024 * 1024);
    _Float16*  ph    = (_Float16*)(ws + 262144 + 20u * 1024 * 1024);

    hipLaunchKernelGGL(prep_kernel, dim3(NTOT / 256), dim3(256), 0, stream,
                       x, W, sq, xh, xh2, Wh, stats);
    hipLaunchKernelGGL(knn_scan_mfma_kernel, dim3(256 * 3), dim3(512), 0, stream,
                       xh, xh2, sq, sub_k);
    hipLaunchKernelGGL(rescue_pool_gemm_stats_kernel, dim3(NTOT / 64), dim3(256), 0, stream,
                       x, xh, sq, sub_k, Wh, bias, ph, stats);
    hipLaunchKernelGGL(gemm_bn_out_kernel, dim3(NTOT / 16), dim3(64), 0, stream,
                       ph, Wh, stats, bias, gamma, beta, out);
}